// Round 9
// baseline (136.888 us; speedup 1.0000x reference)
//
#include <hip/hip_runtime.h>

// MeanGraphSage: h = relu(concat(x @ Ws, mean_neighbors @ Wn) + bias)
// N=50000 nodes, E=800000 edges, D=64 in-feats, 128 out (64+64 concat).
//
// Round 9: aggregate is latency/issue-bound, not byte-bound (r7: 2 TB/s
// effective, VALUBusy 24%) -> bf16 gave ~0. Restructure instead:
//  - prep: x_to_bf16 + bucket_hist fused (one launch).
//  - sage_fused: aggregate + BOTH projections + bias + relu in one kernel.
//    Wave-per-node: bf16 gather (round-8 path) -> mean+x staged in per-wave
//    LDS (wave-wide DS ops; compiler orders via lgkmcnt, no barrier) ->
//    lanes 0-31 emit self outputs (pairs), lanes 32-63 neighbor outputs,
//    reading bf16-packed kernels from 16KB LDS (2-way aliasing = free).
//    Kills the 25.6MB mean round-trip, the whole project pass + barriers,
//    and 2 launches. 18KB LDS -> 8 blocks/CU, 32 waves/CU (max).

typedef unsigned long long ull;

constexpr int N_NODES = 50000;
constexpr int N_EDGES = 800000;
constexpr int D = 64;
constexpr int UNITS = 128;
constexpr int NB = (N_NODES + 255) / 256;           // 196 buckets of 256 nodes
constexpr int SC_EPT = 16;                           // scatter: edges/thread
constexpr int SC_THREADS = 256;
constexpr int SC_CHUNK = SC_EPT * SC_THREADS;        // 4096
constexpr int SC_BLOCKS = (N_EDGES + SC_CHUNK - 1) / SC_CHUNK;  // 196
constexpr int NS_THREADS = 256;
constexpr int NS_EPT = 24;                           // bucket capacity 6144
constexpr int FB_BLOCKS = 2048;
constexpr int FB_WAVES  = FB_BLOCKS * 4;             // 8192
constexpr int NPW = (N_NODES + FB_WAVES - 1) / FB_WAVES;  // 7 nodes/wave
constexpr int PREP_BLOCKS = 2048;

__device__ __forceinline__ unsigned f2bf(float f) {   // RNE f32 -> bf16 bits
    unsigned u = __float_as_uint(f);
    return (u + 0x7fffu + ((u >> 16) & 1u)) >> 16;
}
__device__ __forceinline__ float bf2f(unsigned b) {   // bf16 bits -> f32
    return __uint_as_float(b << 16);
}

// ---------------- prep: x->bf16 table + bucket histogram ----------------
__global__ __launch_bounds__(256) void prep(const float* __restrict__ x,
                                            unsigned* __restrict__ xh,
                                            const int* __restrict__ ei,
                                            int* __restrict__ partial) {
    constexpr int XW = N_NODES * (D / 2);   // 1.6M packed words
    for (int i = blockIdx.x * 256 + threadIdx.x; i < XW; i += PREP_BLOCKS * 256) {
        const float2 v = ((const float2*)x)[i];
        xh[i] = f2bf(v.x) | (f2bf(v.y) << 16);
    }
    if (blockIdx.x < SC_BLOCKS) {
        __shared__ int lh[NB];
        for (int i = threadIdx.x; i < NB; i += 256) lh[i] = 0;
        __syncthreads();
        const int e0 = blockIdx.x * SC_CHUNK + threadIdx.x;
        #pragma unroll
        for (int i = 0; i < SC_EPT; ++i) {
            int e = e0 + i * SC_THREADS;
            if (e < N_EDGES) atomicAdd(&lh[ei[e] >> 8], 1);
        }
        __syncthreads();
        int* row = partial + (size_t)blockIdx.x * NB;
        for (int i = threadIdx.x; i < NB; i += 256) row[i] = lh[i];
    }
}

// ---------------- column scan (in place) + bucket scan -> boffs ----------------
__global__ __launch_bounds__(256) void bucket_scan(int* __restrict__ partial,
                                                   int* __restrict__ boffs) {
    __shared__ int s[256];
    const int t = threadIdx.x;
    int run = 0;
    if (t < NB) {
        for (int b = 0; b < SC_BLOCKS; ++b) {
            const size_t idx = (size_t)b * NB + t;   // coalesced across t
            const int v = partial[idx];
            partial[idx] = run;                      // exclusive within-bucket base
            run += v;
        }
    }
    s[t] = (t < NB) ? run : 0;
    __syncthreads();
    for (int d2 = 1; d2 < 256; d2 <<= 1) {
        int u = (t >= d2) ? s[t - d2] : 0;
        __syncthreads();
        s[t] += u;
        __syncthreads();
    }
    if (t < NB) {
        boffs[t] = s[t] - run;
        if (t == NB - 1) boffs[NB] = s[t];
    }
}

// ---------------- single-pass scatter into bucket runs ----------------
// pack: hi32 = col(16b) | r8<<16 ; lo32 = f32 weight bits
__global__ __launch_bounds__(SC_THREADS) void edge_scatter(const int* __restrict__ ei,
                                                           const float* __restrict__ ew,
                                                           const int* __restrict__ partial,
                                                           const int* __restrict__ boffs,
                                                           ull* __restrict__ packed) {
    __shared__ int lbase[NB];
    __shared__ int lcur[NB];
    const int t = threadIdx.x;
    const int* row = partial + (size_t)blockIdx.x * NB;
    for (int i = t; i < NB; i += SC_THREADS) {
        lbase[i] = boffs[i] + row[i];
        lcur[i]  = 0;
    }
    __syncthreads();
    const int e0 = blockIdx.x * SC_CHUNK + t;
    #pragma unroll
    for (int i = 0; i < SC_EPT; ++i) {
        const int e = e0 + i * SC_THREADS;
        if (e < N_EDGES) {
            const int   r = ei[e];
            const int   c = ei[N_EDGES + e];
            const float w = ew[e];
            const int   b = r >> 8;
            const int   lpos = atomicAdd(&lcur[b], 1);
            const unsigned hi = (unsigned)c | ((unsigned)(r & 255) << 16);
            packed[lbase[b] + lpos] = ((ull)hi << 32) | (ull)(unsigned)__float_as_uint(w);
        }
    }
}

// ---------------- within-bucket node sort + CSR offsets + 4B compaction ----
__global__ __launch_bounds__(NS_THREADS) void node_sort(const int* __restrict__ boffs,
                                                        int* __restrict__ offs,
                                                        const ull* __restrict__ packed,
                                                        unsigned* __restrict__ cedges) {
    __shared__ int cur[256];
    __shared__ int sc[256];
    const int b = blockIdx.x;
    const int s = boffs[b];
    const int e = boffs[b + 1];
    const int t = threadIdx.x;

    ull st[NS_EPT];
    #pragma unroll
    for (int i = 0; i < NS_EPT; ++i) {
        const int idx = s + t + i * NS_THREADS;
        st[i] = (idx < e) ? packed[idx] : ~0ull;   // sentinel
    }
    cur[t] = 0;
    __syncthreads();
    #pragma unroll
    for (int i = 0; i < NS_EPT; ++i) {
        if (st[i] != ~0ull) atomicAdd(&cur[(int)((st[i] >> 48) & 0xff)], 1);
    }
    __syncthreads();
    const int v = cur[t];
    sc[t] = v;
    __syncthreads();
    for (int d2 = 1; d2 < 256; d2 <<= 1) {
        int u = (t >= d2) ? sc[t - d2] : 0;
        __syncthreads();
        sc[t] += u;
        __syncthreads();
    }
    const int excl = sc[t] - v;
    const int n = b * 256 + t;
    if (n < N_NODES) offs[n] = s + excl;
    if (b == NB - 1 && t == 0) offs[N_NODES] = e;
    cur[t] = excl;          // per-node cursor
    __syncthreads();
    #pragma unroll
    for (int i = 0; i < NS_EPT; ++i) {
        if (st[i] != ~0ull) {
            const int r8  = (int)((st[i] >> 48) & 0xff);
            const int pos = atomicAdd(&cur[r8], 1);
            const unsigned hi  = (unsigned)(st[i] >> 32);
            const unsigned col = hi & 0xffffu;
            const unsigned wbf = f2bf(__uint_as_float((unsigned)st[i]));
            cedges[s + pos] = (col << 16) | wbf;
        }
    }
}

// ---------------- fused aggregate + dual projection + bias + relu ----------
// Wave-per-node (NPW consecutive nodes per wave). Gather mean via bf16
// half-wave path; stage x-row + mean in per-wave LDS (wave-wide ds ops, no
// block barrier needed); lanes 0..31 compute self output pairs, lanes 32..63
// neighbor output pairs, reading bf16-packed kernels from LDS.
__global__ __launch_bounds__(256) void sage_fused(const float* __restrict__ x,
                                                  const unsigned* __restrict__ xh,
                                                  const int* __restrict__ offs,
                                                  const unsigned* __restrict__ cedges,
                                                  const float* __restrict__ skern,
                                                  const float* __restrict__ nkern,
                                                  const float* __restrict__ bias,
                                                  float* __restrict__ out) {
    __shared__ unsigned kpack[D][64];   // [k][0..31]=self pairs, [32..63]=neigh pairs; 16KB
    __shared__ float feats[4][UNITS];   // [wave][0..63]=x row, [64..127]=mean; 2KB
    const int t = threadIdx.x;
    for (int i = t; i < D * 32; i += 256) {
        const int k = i >> 5, p = i & 31;
        kpack[k][p]      = f2bf(skern[k * 64 + 2 * p]) | (f2bf(skern[k * 64 + 2 * p + 1]) << 16);
        kpack[k][32 + p] = f2bf(nkern[k * 64 + 2 * p]) | (f2bf(nkern[k * 64 + 2 * p + 1]) << 16);
    }
    __syncthreads();

    const int lane = t & 63;
    const int wv   = t >> 6;
    const int half = lane >> 5;
    const int fp   = lane & 31;
    const float b0 = bias[(half ? 64 : 0) + 2 * fp];
    const float b1 = bias[(half ? 64 : 0) + 2 * fp + 1];

    const int gw = blockIdx.x * 4 + wv;
    const int nlo = gw * NPW;
    const int nhi = min(nlo + NPW, N_NODES);

    for (int n = nlo; n < nhi; ++n) {
        const int s    = offs[n];
        const int eend = offs[n + 1];
        // ---- bf16 gather: half-wave h handles edge e+h; lane owns feat pair fp
        float a0x = 0.f, a0y = 0.f, a1x = 0.f, a1y = 0.f;
        int e = s;
        for (; e + 3 < eend; e += 4) {
            const unsigned c0 = cedges[e + half];
            const unsigned c1 = cedges[e + 2 + half];
            const unsigned v0 = xh[(c0 >> 16) * (D / 2) + fp];
            const unsigned v1 = xh[(c1 >> 16) * (D / 2) + fp];
            const float w0 = bf2f(c0 & 0xffffu);
            const float w1 = bf2f(c1 & 0xffffu);
            a0x = fmaf(__uint_as_float(v0 << 16),         w0, a0x);
            a0y = fmaf(__uint_as_float(v0 & 0xffff0000u), w0, a0y);
            a1x = fmaf(__uint_as_float(v1 << 16),         w1, a1x);
            a1y = fmaf(__uint_as_float(v1 & 0xffff0000u), w1, a1y);
        }
        for (; e < eend; ++e) {
            if (half == 0) {
                const unsigned c = cedges[e];
                const unsigned v = xh[(c >> 16) * (D / 2) + fp];
                const float w = bf2f(c & 0xffffu);
                a0x = fmaf(__uint_as_float(v << 16),         w, a0x);
                a0y = fmaf(__uint_as_float(v & 0xffff0000u), w, a0y);
            }
        }
        float ax = a0x + a1x;
        float ay = a0y + a1y;
        ax += __shfl_xor(ax, 32);
        ay += __shfl_xor(ay, 32);

        // ---- stage features in per-wave LDS (same-wave ds ordering via lgkmcnt)
        feats[wv][lane] = x[n * D + lane];
        if (half == 0) {
            const float inv = 1.0f / fmaxf((float)(eend - s), 1.0f);
            feats[wv][64 + 2 * fp]     = ax * inv;
            feats[wv][64 + 2 * fp + 1] = ay * inv;
        }

        // ---- projection: lane produces outputs (2fp, 2fp+1) of its half
        const int fbase = half ? 64 : 0;    // self half reads x, neigh half reads mean
        float o0 = 0.f, o1 = 0.f;
        #pragma unroll
        for (int k = 0; k < D; ++k) {
            const float    f  = feats[wv][fbase + k];   // 2-address broadcast
            const unsigned kw = kpack[k][lane];         // 2-way bank alias (free)
            o0 = fmaf(f, __uint_as_float(kw << 16),         o0);
            o1 = fmaf(f, __uint_as_float(kw & 0xffff0000u), o1);
        }
        float2 r = make_float2(fmaxf(o0 + b0, 0.f), fmaxf(o1 + b1, 0.f));
        *(float2*)&out[n * UNITS + (half ? 64 : 0) + 2 * fp] = r;
    }
}

extern "C" void kernel_launch(void* const* d_in, const int* in_sizes, int n_in,
                              void* d_out, int out_size, void* d_ws, size_t ws_size,
                              hipStream_t stream) {
    const float* x     = (const float*)d_in[0];
    const int*   ei    = (const int*)  d_in[1];
    const float* ew    = (const float*)d_in[2];
    const float* skern = (const float*)d_in[3];
    const float* nkern = (const float*)d_in[4];
    const float* bias  = (const float*)d_in[5];
    float* out = (float*)d_out;

    auto align256 = [](size_t v) { return (v + 255) & ~size_t(255); };
    const size_t szM  = align256((size_t)SC_BLOCKS * NB * sizeof(int));   // partials matrix
    const size_t szO  = align256((size_t)(NB + 1) * sizeof(int));
    const size_t szNO = align256((size_t)(N_NODES + 1) * sizeof(int));
    const size_t szP  = align256((size_t)N_EDGES * sizeof(ull));
    const size_t szC  = align256((size_t)N_EDGES * sizeof(unsigned));

    char* w = (char*)d_ws;
    int*      partial = (int*)w;
    int*      boffs   = (int*)(w + szM);
    int*      offs    = (int*)(w + szM + szO);
    ull*      packed  = (ull*)(w + szM + szO + szNO);
    unsigned* cedges  = (unsigned*)(w + szM + szO + szNO + szP);
    unsigned* xh      = (unsigned*)(w + szM + szO + szNO + szP + szC);
    (void)ws_size; (void)in_sizes; (void)n_in; (void)out_size;

    prep        <<<PREP_BLOCKS, 256, 0, stream>>>(x, xh, ei, partial);
    bucket_scan <<<1, 256, 0, stream>>>(partial, boffs);
    edge_scatter<<<SC_BLOCKS, SC_THREADS, 0, stream>>>(ei, ew, partial, boffs, packed);
    node_sort   <<<NB, NS_THREADS, 0, stream>>>(boffs, offs, packed, cedges);
    sage_fused  <<<FB_BLOCKS, 256, 0, stream>>>(x, xh, offs, cedges, skern, nkern, bias, out);
}

// Round 10
// 86.430 us; speedup vs baseline: 1.5838x; 1.5838x over previous
//
#include <hip/hip_runtime.h>

// MeanGraphSage: h = relu(concat(x @ Ws, mean_neighbors @ Wn) + bias)
// N=50000 nodes, E=800000 edges, D=64 in-feats, 128 out (64+64 concat).
//
// Round 10: revert round-9 fusion (latency exposure worsened; 100us fused).
// Keep round-8 pipeline; two changes:
//  - prep: x_to_bf16 + bucket_hist in one launch (r9's good piece).
//  - sage_aggregate: HALF-WAVE-per-node. Each 32-lane half owns its own
//    node; lane owns a feature pair; 4 independent chains -> 4 outstanding
//    128B row gathers per half (8/wave, 2-4x the MLP of wave-per-node).
//    No shfl combine, no cross-half remainder divergence.

typedef unsigned long long ull;

constexpr int N_NODES = 50000;
constexpr int N_EDGES = 800000;
constexpr int D = 64;
constexpr int UNITS = 128;
constexpr int NB = (N_NODES + 255) / 256;           // 196 buckets of 256 nodes
constexpr int SC_EPT = 16;                           // scatter: edges/thread
constexpr int SC_THREADS = 256;
constexpr int SC_CHUNK = SC_EPT * SC_THREADS;        // 4096
constexpr int SC_BLOCKS = (N_EDGES + SC_CHUNK - 1) / SC_CHUNK;  // 196
constexpr int NS_THREADS = 256;
constexpr int NS_EPT = 24;                           // bucket capacity 6144
constexpr int PREP_BLOCKS = 2048;

__device__ __forceinline__ unsigned f2bf(float f) {   // RNE f32 -> bf16 bits
    unsigned u = __float_as_uint(f);
    return (u + 0x7fffu + ((u >> 16) & 1u)) >> 16;
}
__device__ __forceinline__ float bf2f(unsigned b) {   // bf16 bits -> f32
    return __uint_as_float(b << 16);
}

// ---------------- prep: x->bf16 table + bucket histogram ----------------
__global__ __launch_bounds__(256) void prep(const float* __restrict__ x,
                                            unsigned* __restrict__ xh,
                                            const int* __restrict__ ei,
                                            int* __restrict__ partial) {
    constexpr int XW = N_NODES * (D / 2);   // 1.6M packed words
    for (int i = blockIdx.x * 256 + threadIdx.x; i < XW; i += PREP_BLOCKS * 256) {
        const float2 v = ((const float2*)x)[i];
        xh[i] = f2bf(v.x) | (f2bf(v.y) << 16);
    }
    if (blockIdx.x < SC_BLOCKS) {
        __shared__ int lh[NB];
        for (int i = threadIdx.x; i < NB; i += 256) lh[i] = 0;
        __syncthreads();
        const int e0 = blockIdx.x * SC_CHUNK + threadIdx.x;
        #pragma unroll
        for (int i = 0; i < SC_EPT; ++i) {
            int e = e0 + i * SC_THREADS;
            if (e < N_EDGES) atomicAdd(&lh[ei[e] >> 8], 1);
        }
        __syncthreads();
        int* row = partial + (size_t)blockIdx.x * NB;
        for (int i = threadIdx.x; i < NB; i += 256) row[i] = lh[i];
    }
}

// ---------------- column scan (in place) + bucket scan -> boffs ----------------
__global__ __launch_bounds__(256) void bucket_scan(int* __restrict__ partial,
                                                   int* __restrict__ boffs) {
    __shared__ int s[256];
    const int t = threadIdx.x;
    int run = 0;
    if (t < NB) {
        for (int b = 0; b < SC_BLOCKS; ++b) {
            const size_t idx = (size_t)b * NB + t;   // coalesced across t
            const int v = partial[idx];
            partial[idx] = run;                      // exclusive within-bucket base
            run += v;
        }
    }
    s[t] = (t < NB) ? run : 0;
    __syncthreads();
    for (int d2 = 1; d2 < 256; d2 <<= 1) {
        int u = (t >= d2) ? s[t - d2] : 0;
        __syncthreads();
        s[t] += u;
        __syncthreads();
    }
    if (t < NB) {
        boffs[t] = s[t] - run;
        if (t == NB - 1) boffs[NB] = s[t];
    }
}

// ---------------- single-pass scatter into bucket runs ----------------
// pack: hi32 = col(16b) | r8<<16 ; lo32 = f32 weight bits
__global__ __launch_bounds__(SC_THREADS) void edge_scatter(const int* __restrict__ ei,
                                                           const float* __restrict__ ew,
                                                           const int* __restrict__ partial,
                                                           const int* __restrict__ boffs,
                                                           ull* __restrict__ packed) {
    __shared__ int lbase[NB];
    __shared__ int lcur[NB];
    const int t = threadIdx.x;
    const int* row = partial + (size_t)blockIdx.x * NB;
    for (int i = t; i < NB; i += SC_THREADS) {
        lbase[i] = boffs[i] + row[i];
        lcur[i]  = 0;
    }
    __syncthreads();
    const int e0 = blockIdx.x * SC_CHUNK + t;
    #pragma unroll
    for (int i = 0; i < SC_EPT; ++i) {
        const int e = e0 + i * SC_THREADS;
        if (e < N_EDGES) {
            const int   r = ei[e];
            const int   c = ei[N_EDGES + e];
            const float w = ew[e];
            const int   b = r >> 8;
            const int   lpos = atomicAdd(&lcur[b], 1);
            const unsigned hi = (unsigned)c | ((unsigned)(r & 255) << 16);
            packed[lbase[b] + lpos] = ((ull)hi << 32) | (ull)(unsigned)__float_as_uint(w);
        }
    }
}

// ---------------- within-bucket node sort + CSR offsets + 4B compaction ----
__global__ __launch_bounds__(NS_THREADS) void node_sort(const int* __restrict__ boffs,
                                                        int* __restrict__ offs,
                                                        const ull* __restrict__ packed,
                                                        unsigned* __restrict__ cedges) {
    __shared__ int cur[256];
    __shared__ int sc[256];
    const int b = blockIdx.x;
    const int s = boffs[b];
    const int e = boffs[b + 1];
    const int t = threadIdx.x;

    ull st[NS_EPT];
    #pragma unroll
    for (int i = 0; i < NS_EPT; ++i) {
        const int idx = s + t + i * NS_THREADS;
        st[i] = (idx < e) ? packed[idx] : ~0ull;   // sentinel
    }
    cur[t] = 0;
    __syncthreads();
    #pragma unroll
    for (int i = 0; i < NS_EPT; ++i) {
        if (st[i] != ~0ull) atomicAdd(&cur[(int)((st[i] >> 48) & 0xff)], 1);
    }
    __syncthreads();
    const int v = cur[t];
    sc[t] = v;
    __syncthreads();
    for (int d2 = 1; d2 < 256; d2 <<= 1) {
        int u = (t >= d2) ? sc[t - d2] : 0;
        __syncthreads();
        sc[t] += u;
        __syncthreads();
    }
    const int excl = sc[t] - v;
    const int n = b * 256 + t;
    if (n < N_NODES) offs[n] = s + excl;
    if (b == NB - 1 && t == 0) offs[N_NODES] = e;
    cur[t] = excl;          // per-node cursor
    __syncthreads();
    #pragma unroll
    for (int i = 0; i < NS_EPT; ++i) {
        if (st[i] != ~0ull) {
            const int r8  = (int)((st[i] >> 48) & 0xff);
            const int pos = atomicAdd(&cur[r8], 1);
            const unsigned hi  = (unsigned)(st[i] >> 32);
            const unsigned col = hi & 0xffffu;
            const unsigned wbf = f2bf(__uint_as_float((unsigned)st[i]));
            cedges[s + pos] = (col << 16) | wbf;
        }
    }
}

// ---------------- half-wave-per-node aggregation (bf16 gathers) ----------
// Half-wave hw owns node n=hw; lane owns feature pair fp; 4 independent
// chains -> 4 outstanding 128B row gathers per half (8 per wave).
__global__ __launch_bounds__(256) void sage_aggregate(const unsigned* __restrict__ xh,
                                                      const int* __restrict__ offs,
                                                      const unsigned* __restrict__ cedges,
                                                      float* __restrict__ out) {
    const int n = (blockIdx.x * 256 + threadIdx.x) >> 5;   // half-wave id
    if (n >= N_NODES) return;
    const int fp = threadIdx.x & 31;
    const int s = offs[n];
    const int t = offs[n + 1];

    float a0x = 0.f, a0y = 0.f, a1x = 0.f, a1y = 0.f;
    float a2x = 0.f, a2y = 0.f, a3x = 0.f, a3y = 0.f;
    int e = s;
    for (; e + 3 < t; e += 4) {
        const unsigned c0 = cedges[e],     c1 = cedges[e + 1];
        const unsigned c2 = cedges[e + 2], c3 = cedges[e + 3];
        const unsigned v0 = xh[(c0 >> 16) * (D / 2) + fp];
        const unsigned v1 = xh[(c1 >> 16) * (D / 2) + fp];
        const unsigned v2 = xh[(c2 >> 16) * (D / 2) + fp];
        const unsigned v3 = xh[(c3 >> 16) * (D / 2) + fp];
        const float w0 = bf2f(c0 & 0xffffu), w1 = bf2f(c1 & 0xffffu);
        const float w2 = bf2f(c2 & 0xffffu), w3 = bf2f(c3 & 0xffffu);
        a0x = fmaf(__uint_as_float(v0 << 16),         w0, a0x);
        a0y = fmaf(__uint_as_float(v0 & 0xffff0000u), w0, a0y);
        a1x = fmaf(__uint_as_float(v1 << 16),         w1, a1x);
        a1y = fmaf(__uint_as_float(v1 & 0xffff0000u), w1, a1y);
        a2x = fmaf(__uint_as_float(v2 << 16),         w2, a2x);
        a2y = fmaf(__uint_as_float(v2 & 0xffff0000u), w2, a2y);
        a3x = fmaf(__uint_as_float(v3 << 16),         w3, a3x);
        a3y = fmaf(__uint_as_float(v3 & 0xffff0000u), w3, a3y);
    }
    for (; e < t; ++e) {
        const unsigned c = cedges[e];
        const unsigned v = xh[(c >> 16) * (D / 2) + fp];
        const float w = bf2f(c & 0xffffu);
        a0x = fmaf(__uint_as_float(v << 16),         w, a0x);
        a0y = fmaf(__uint_as_float(v & 0xffff0000u), w, a0y);
    }
    const float inv = 1.0f / fmaxf((float)(t - s), 1.0f);
    float2 m = make_float2(((a0x + a1x) + (a2x + a3x)) * inv,
                           ((a0y + a1y) + (a2y + a3y)) * inv);
    *(float2*)&out[n * UNITS + D + 2 * fp] = m;
}

// ---------------- projection ----------------
// Neighbor half of out already holds the MEAN.
__global__ __launch_bounds__(256) void sage_project(const float* __restrict__ x,
                                                    const float* __restrict__ skern,
                                                    const float* __restrict__ nkern,
                                                    const float* __restrict__ bias,
                                                    float* __restrict__ out) {
    const int tg = threadIdx.x >> 7;
    const int j  = threadIdx.x & 127;
    const int jj = j & (D - 1);
    const float* K = (j < D) ? skern : nkern;

    float kcol[D];
    #pragma unroll
    for (int k = 0; k < D; ++k) kcol[k] = K[k * D + jj];
    const float bj = bias[j];
    const int base = (j < D) ? 0 : D;

    __shared__ float feat[2][UNITS];

    for (int n = blockIdx.x * 2 + tg; n < N_NODES; n += gridDim.x * 2) {
        if (j < D) {
            feat[tg][j] = x[n * D + j];
        } else {
            feat[tg][j] = out[n * UNITS + j];
        }
        __syncthreads();
        float acc2 = 0.0f;
        #pragma unroll
        for (int k = 0; k < D; ++k) acc2 += feat[tg][base + k] * kcol[k];
        acc2 += bj;
        out[n * UNITS + j] = fmaxf(acc2, 0.0f);
        __syncthreads();
    }
}

extern "C" void kernel_launch(void* const* d_in, const int* in_sizes, int n_in,
                              void* d_out, int out_size, void* d_ws, size_t ws_size,
                              hipStream_t stream) {
    const float* x     = (const float*)d_in[0];
    const int*   ei    = (const int*)  d_in[1];
    const float* ew    = (const float*)d_in[2];
    const float* skern = (const float*)d_in[3];
    const float* nkern = (const float*)d_in[4];
    const float* bias  = (const float*)d_in[5];
    float* out = (float*)d_out;

    auto align256 = [](size_t v) { return (v + 255) & ~size_t(255); };
    const size_t szM  = align256((size_t)SC_BLOCKS * NB * sizeof(int));   // partials matrix
    const size_t szO  = align256((size_t)(NB + 1) * sizeof(int));
    const size_t szNO = align256((size_t)(N_NODES + 1) * sizeof(int));
    const size_t szP  = align256((size_t)N_EDGES * sizeof(ull));
    const size_t szC  = align256((size_t)N_EDGES * sizeof(unsigned));

    char* w = (char*)d_ws;
    int*      partial = (int*)w;
    int*      boffs   = (int*)(w + szM);
    int*      offs    = (int*)(w + szM + szO);
    ull*      packed  = (ull*)(w + szM + szO + szNO);
    unsigned* cedges  = (unsigned*)(w + szM + szO + szNO + szP);
    unsigned* xh      = (unsigned*)(w + szM + szO + szNO + szP + szC);
    (void)ws_size; (void)in_sizes; (void)n_in; (void)out_size;

    prep          <<<PREP_BLOCKS, 256, 0, stream>>>(x, xh, ei, partial);
    bucket_scan   <<<1, 256, 0, stream>>>(partial, boffs);
    edge_scatter  <<<SC_BLOCKS, SC_THREADS, 0, stream>>>(ei, ew, partial, boffs, packed);
    node_sort     <<<NB, NS_THREADS, 0, stream>>>(boffs, offs, packed, cedges);
    sage_aggregate<<<(N_NODES * 32 + 255) / 256, 256, 0, stream>>>(xh, offs, cedges, out);
    sage_project  <<<2048, 256, 0, stream>>>(x, skern, nkern, bias, out);
}

// Round 11
// 83.911 us; speedup vs baseline: 1.6313x; 1.0300x over previous
//
#include <hip/hip_runtime.h>

// MeanGraphSage: h = relu(concat(x @ Ws, mean_neighbors @ Wn) + bias)
// N=50000 nodes, E=800000 edges, D=64 in-feats, 128 out (64+64 concat).
//
// Round 11: bucket_scan (1 block, 196 serial dependent load+store iters over
// the 196x196 partials matrix) was a single-CU latency kernel -- same
// pathology as round-2's 82us scan. Replace with:
//   scan_cols (196 blocks): parallel column scan, in-place exclusive bases.
//   scan_tops (1 tiny block): scan of 196 bucket totals -> boffs.
// Everything else identical to round 10 (86.4us).

typedef unsigned long long ull;

constexpr int N_NODES = 50000;
constexpr int N_EDGES = 800000;
constexpr int D = 64;
constexpr int UNITS = 128;
constexpr int NB = (N_NODES + 255) / 256;           // 196 buckets of 256 nodes
constexpr int SC_EPT = 16;                           // scatter: edges/thread
constexpr int SC_THREADS = 256;
constexpr int SC_CHUNK = SC_EPT * SC_THREADS;        // 4096
constexpr int SC_BLOCKS = (N_EDGES + SC_CHUNK - 1) / SC_CHUNK;  // 196
constexpr int NS_THREADS = 256;
constexpr int NS_EPT = 24;                           // bucket capacity 6144
constexpr int PREP_BLOCKS = 2048;

__device__ __forceinline__ unsigned f2bf(float f) {   // RNE f32 -> bf16 bits
    unsigned u = __float_as_uint(f);
    return (u + 0x7fffu + ((u >> 16) & 1u)) >> 16;
}
__device__ __forceinline__ float bf2f(unsigned b) {   // bf16 bits -> f32
    return __uint_as_float(b << 16);
}

// ---------------- prep: x->bf16 table + bucket histogram ----------------
__global__ __launch_bounds__(256) void prep(const float* __restrict__ x,
                                            unsigned* __restrict__ xh,
                                            const int* __restrict__ ei,
                                            int* __restrict__ partial) {
    constexpr int XW = N_NODES * (D / 2);   // 1.6M packed words
    for (int i = blockIdx.x * 256 + threadIdx.x; i < XW; i += PREP_BLOCKS * 256) {
        const float2 v = ((const float2*)x)[i];
        xh[i] = f2bf(v.x) | (f2bf(v.y) << 16);
    }
    if (blockIdx.x < SC_BLOCKS) {
        __shared__ int lh[NB];
        for (int i = threadIdx.x; i < NB; i += 256) lh[i] = 0;
        __syncthreads();
        const int e0 = blockIdx.x * SC_CHUNK + threadIdx.x;
        #pragma unroll
        for (int i = 0; i < SC_EPT; ++i) {
            int e = e0 + i * SC_THREADS;
            if (e < N_EDGES) atomicAdd(&lh[ei[e] >> 8], 1);
        }
        __syncthreads();
        int* row = partial + (size_t)blockIdx.x * NB;
        for (int i = threadIdx.x; i < NB; i += 256) row[i] = lh[i];
    }
}

// ---------------- parallel column scan: per-(block,bucket) bases ----------
// Block b owns bucket b: loads its 196-entry column concurrently, block-scans,
// writes exclusive prefixes back in place; emits bucket total.
__global__ __launch_bounds__(256) void scan_cols(int* __restrict__ partial,
                                                 int* __restrict__ btot) {
    __shared__ int s[256];
    const int b = blockIdx.x;
    const int t = threadIdx.x;
    const int v = (t < SC_BLOCKS) ? partial[(size_t)t * NB + b] : 0;
    s[t] = v;
    __syncthreads();
    for (int d2 = 1; d2 < 256; d2 <<= 1) {
        int u = (t >= d2) ? s[t - d2] : 0;
        __syncthreads();
        s[t] += u;
        __syncthreads();
    }
    if (t < SC_BLOCKS) partial[(size_t)t * NB + b] = s[t] - v;
    if (t == 255) btot[b] = s[255];
}

// ---------------- scan of 196 bucket totals -> boffs ----------------
__global__ __launch_bounds__(256) void scan_tops(const int* __restrict__ btot,
                                                 int* __restrict__ boffs) {
    __shared__ int s[256];
    const int t = threadIdx.x;
    const int v = (t < NB) ? btot[t] : 0;
    s[t] = v;
    __syncthreads();
    for (int d2 = 1; d2 < 256; d2 <<= 1) {
        int u = (t >= d2) ? s[t - d2] : 0;
        __syncthreads();
        s[t] += u;
        __syncthreads();
    }
    if (t < NB) {
        boffs[t] = s[t] - v;
        if (t == NB - 1) boffs[NB] = s[t];
    }
}

// ---------------- single-pass scatter into bucket runs ----------------
// pack: hi32 = col(16b) | r8<<16 ; lo32 = f32 weight bits
__global__ __launch_bounds__(SC_THREADS) void edge_scatter(const int* __restrict__ ei,
                                                           const float* __restrict__ ew,
                                                           const int* __restrict__ partial,
                                                           const int* __restrict__ boffs,
                                                           ull* __restrict__ packed) {
    __shared__ int lbase[NB];
    __shared__ int lcur[NB];
    const int t = threadIdx.x;
    const int* row = partial + (size_t)blockIdx.x * NB;
    for (int i = t; i < NB; i += SC_THREADS) {
        lbase[i] = boffs[i] + row[i];
        lcur[i]  = 0;
    }
    __syncthreads();
    const int e0 = blockIdx.x * SC_CHUNK + t;
    #pragma unroll
    for (int i = 0; i < SC_EPT; ++i) {
        const int e = e0 + i * SC_THREADS;
        if (e < N_EDGES) {
            const int   r = ei[e];
            const int   c = ei[N_EDGES + e];
            const float w = ew[e];
            const int   b = r >> 8;
            const int   lpos = atomicAdd(&lcur[b], 1);
            const unsigned hi = (unsigned)c | ((unsigned)(r & 255) << 16);
            packed[lbase[b] + lpos] = ((ull)hi << 32) | (ull)(unsigned)__float_as_uint(w);
        }
    }
}

// ---------------- within-bucket node sort + CSR offsets + 4B compaction ----
__global__ __launch_bounds__(NS_THREADS) void node_sort(const int* __restrict__ boffs,
                                                        int* __restrict__ offs,
                                                        const ull* __restrict__ packed,
                                                        unsigned* __restrict__ cedges) {
    __shared__ int cur[256];
    __shared__ int sc[256];
    const int b = blockIdx.x;
    const int s = boffs[b];
    const int e = boffs[b + 1];
    const int t = threadIdx.x;

    ull st[NS_EPT];
    #pragma unroll
    for (int i = 0; i < NS_EPT; ++i) {
        const int idx = s + t + i * NS_THREADS;
        st[i] = (idx < e) ? packed[idx] : ~0ull;   // sentinel
    }
    cur[t] = 0;
    __syncthreads();
    #pragma unroll
    for (int i = 0; i < NS_EPT; ++i) {
        if (st[i] != ~0ull) atomicAdd(&cur[(int)((st[i] >> 48) & 0xff)], 1);
    }
    __syncthreads();
    const int v = cur[t];
    sc[t] = v;
    __syncthreads();
    for (int d2 = 1; d2 < 256; d2 <<= 1) {
        int u = (t >= d2) ? sc[t - d2] : 0;
        __syncthreads();
        sc[t] += u;
        __syncthreads();
    }
    const int excl = sc[t] - v;
    const int n = b * 256 + t;
    if (n < N_NODES) offs[n] = s + excl;
    if (b == NB - 1 && t == 0) offs[N_NODES] = e;
    cur[t] = excl;          // per-node cursor
    __syncthreads();
    #pragma unroll
    for (int i = 0; i < NS_EPT; ++i) {
        if (st[i] != ~0ull) {
            const int r8  = (int)((st[i] >> 48) & 0xff);
            const int pos = atomicAdd(&cur[r8], 1);
            const unsigned hi  = (unsigned)(st[i] >> 32);
            const unsigned col = hi & 0xffffu;
            const unsigned wbf = f2bf(__uint_as_float((unsigned)st[i]));
            cedges[s + pos] = (col << 16) | wbf;
        }
    }
}

// ---------------- half-wave-per-node aggregation (bf16 gathers) ----------
__global__ __launch_bounds__(256) void sage_aggregate(const unsigned* __restrict__ xh,
                                                      const int* __restrict__ offs,
                                                      const unsigned* __restrict__ cedges,
                                                      float* __restrict__ out) {
    const int n = (blockIdx.x * 256 + threadIdx.x) >> 5;   // half-wave id
    if (n >= N_NODES) return;
    const int fp = threadIdx.x & 31;
    const int s = offs[n];
    const int t = offs[n + 1];

    float a0x = 0.f, a0y = 0.f, a1x = 0.f, a1y = 0.f;
    float a2x = 0.f, a2y = 0.f, a3x = 0.f, a3y = 0.f;
    int e = s;
    for (; e + 3 < t; e += 4) {
        const unsigned c0 = cedges[e],     c1 = cedges[e + 1];
        const unsigned c2 = cedges[e + 2], c3 = cedges[e + 3];
        const unsigned v0 = xh[(c0 >> 16) * (D / 2) + fp];
        const unsigned v1 = xh[(c1 >> 16) * (D / 2) + fp];
        const unsigned v2 = xh[(c2 >> 16) * (D / 2) + fp];
        const unsigned v3 = xh[(c3 >> 16) * (D / 2) + fp];
        const float w0 = bf2f(c0 & 0xffffu), w1 = bf2f(c1 & 0xffffu);
        const float w2 = bf2f(c2 & 0xffffu), w3 = bf2f(c3 & 0xffffu);
        a0x = fmaf(__uint_as_float(v0 << 16),         w0, a0x);
        a0y = fmaf(__uint_as_float(v0 & 0xffff0000u), w0, a0y);
        a1x = fmaf(__uint_as_float(v1 << 16),         w1, a1x);
        a1y = fmaf(__uint_as_float(v1 & 0xffff0000u), w1, a1y);
        a2x = fmaf(__uint_as_float(v2 << 16),         w2, a2x);
        a2y = fmaf(__uint_as_float(v2 & 0xffff0000u), w2, a2y);
        a3x = fmaf(__uint_as_float(v3 << 16),         w3, a3x);
        a3y = fmaf(__uint_as_float(v3 & 0xffff0000u), w3, a3y);
    }
    for (; e < t; ++e) {
        const unsigned c = cedges[e];
        const unsigned v = xh[(c >> 16) * (D / 2) + fp];
        const float w = bf2f(c & 0xffffu);
        a0x = fmaf(__uint_as_float(v << 16),         w, a0x);
        a0y = fmaf(__uint_as_float(v & 0xffff0000u), w, a0y);
    }
    const float inv = 1.0f / fmaxf((float)(t - s), 1.0f);
    float2 m = make_float2(((a0x + a1x) + (a2x + a3x)) * inv,
                           ((a0y + a1y) + (a2y + a3y)) * inv);
    *(float2*)&out[n * UNITS + D + 2 * fp] = m;
}

// ---------------- projection ----------------
// Neighbor half of out already holds the MEAN.
__global__ __launch_bounds__(256) void sage_project(const float* __restrict__ x,
                                                    const float* __restrict__ skern,
                                                    const float* __restrict__ nkern,
                                                    const float* __restrict__ bias,
                                                    float* __restrict__ out) {
    const int tg = threadIdx.x >> 7;
    const int j  = threadIdx.x & 127;
    const int jj = j & (D - 1);
    const float* K = (j < D) ? skern : nkern;

    float kcol[D];
    #pragma unroll
    for (int k = 0; k < D; ++k) kcol[k] = K[k * D + jj];
    const float bj = bias[j];
    const int base = (j < D) ? 0 : D;

    __shared__ float feat[2][UNITS];

    for (int n = blockIdx.x * 2 + tg; n < N_NODES; n += gridDim.x * 2) {
        if (j < D) {
            feat[tg][j] = x[n * D + j];
        } else {
            feat[tg][j] = out[n * UNITS + j];
        }
        __syncthreads();
        float acc2 = 0.0f;
        #pragma unroll
        for (int k = 0; k < D; ++k) acc2 += feat[tg][base + k] * kcol[k];
        acc2 += bj;
        out[n * UNITS + j] = fmaxf(acc2, 0.0f);
        __syncthreads();
    }
}

extern "C" void kernel_launch(void* const* d_in, const int* in_sizes, int n_in,
                              void* d_out, int out_size, void* d_ws, size_t ws_size,
                              hipStream_t stream) {
    const float* x     = (const float*)d_in[0];
    const int*   ei    = (const int*)  d_in[1];
    const float* ew    = (const float*)d_in[2];
    const float* skern = (const float*)d_in[3];
    const float* nkern = (const float*)d_in[4];
    const float* bias  = (const float*)d_in[5];
    float* out = (float*)d_out;

    auto align256 = [](size_t v) { return (v + 255) & ~size_t(255); };
    const size_t szM  = align256((size_t)SC_BLOCKS * NB * sizeof(int));   // partials matrix
    const size_t szO  = align256((size_t)(NB + 1) * sizeof(int));
    const size_t szT  = align256((size_t)NB * sizeof(int));               // bucket totals
    const size_t szNO = align256((size_t)(N_NODES + 1) * sizeof(int));
    const size_t szP  = align256((size_t)N_EDGES * sizeof(ull));
    const size_t szC  = align256((size_t)N_EDGES * sizeof(unsigned));

    char* w = (char*)d_ws;
    int*      partial = (int*)w;
    int*      boffs   = (int*)(w + szM);
    int*      btot    = (int*)(w + szM + szO);
    int*      offs    = (int*)(w + szM + szO + szT);
    ull*      packed  = (ull*)(w + szM + szO + szT + szNO);
    unsigned* cedges  = (unsigned*)(w + szM + szO + szT + szNO + szP);
    unsigned* xh      = (unsigned*)(w + szM + szO + szT + szNO + szP + szC);
    (void)ws_size; (void)in_sizes; (void)n_in; (void)out_size;

    prep          <<<PREP_BLOCKS, 256, 0, stream>>>(x, xh, ei, partial);
    scan_cols     <<<NB, 256, 0, stream>>>(partial, btot);
    scan_tops     <<<1, 256, 0, stream>>>(btot, boffs);
    edge_scatter  <<<SC_BLOCKS, SC_THREADS, 0, stream>>>(ei, ew, partial, boffs, packed);
    node_sort     <<<NB, NS_THREADS, 0, stream>>>(boffs, offs, packed, cedges);
    sage_aggregate<<<(N_NODES * 32 + 255) / 256, 256, 0, stream>>>(xh, offs, cedges, out);
    sage_project  <<<2048, 256, 0, stream>>>(x, skern, nkern, bias, out);
}

// Round 12
// 82.080 us; speedup vs baseline: 1.6677x; 1.0223x over previous
//
#include <hip/hip_runtime.h>

// MeanGraphSage: h = relu(concat(x @ Ws, mean_neighbors @ Wn) + bias)
// N=50000 nodes, E=800000 edges, D=64 in-feats, 128 out (64+64 concat).
//
// Round 12 (from 83.9us r11):
//  - scan_tops launch removed: edge_scatter & node_sort recompute the
//    196-bucket offset scan from btot in LDS (cheap, removes a dependent
//    1-block launch).
//  - aggregate: 8 independent chains (8 outstanding 128B gathers per
//    half-wave); writes packed-bf16 mean to meanh (6.4MB) instead of f32
//    into out.
//  - project: stages feats from xh/meanh (bf16) -> 38MB instead of 51MB;
//    out written exactly once.

typedef unsigned long long ull;

constexpr int N_NODES = 50000;
constexpr int N_EDGES = 800000;
constexpr int D = 64;
constexpr int UNITS = 128;
constexpr int NB = (N_NODES + 255) / 256;           // 196 buckets of 256 nodes
constexpr int SC_EPT = 16;                           // scatter: edges/thread
constexpr int SC_THREADS = 256;
constexpr int SC_CHUNK = SC_EPT * SC_THREADS;        // 4096
constexpr int SC_BLOCKS = (N_EDGES + SC_CHUNK - 1) / SC_CHUNK;  // 196
constexpr int NS_THREADS = 256;
constexpr int NS_EPT = 24;                           // bucket capacity 6144
constexpr int PREP_BLOCKS = 2048;

__device__ __forceinline__ unsigned f2bf(float f) {   // RNE f32 -> bf16 bits
    unsigned u = __float_as_uint(f);
    return (u + 0x7fffu + ((u >> 16) & 1u)) >> 16;
}
__device__ __forceinline__ float bf2f(unsigned b) {   // bf16 bits -> f32
    return __uint_as_float(b << 16);
}

// ---------------- prep: x->bf16 table + bucket histogram ----------------
__global__ __launch_bounds__(256) void prep(const float* __restrict__ x,
                                            unsigned* __restrict__ xh,
                                            const int* __restrict__ ei,
                                            int* __restrict__ partial) {
    constexpr int XW = N_NODES * (D / 2);   // 1.6M packed words
    for (int i = blockIdx.x * 256 + threadIdx.x; i < XW; i += PREP_BLOCKS * 256) {
        const float2 v = ((const float2*)x)[i];
        xh[i] = f2bf(v.x) | (f2bf(v.y) << 16);
    }
    if (blockIdx.x < SC_BLOCKS) {
        __shared__ int lh[NB];
        for (int i = threadIdx.x; i < NB; i += 256) lh[i] = 0;
        __syncthreads();
        const int e0 = blockIdx.x * SC_CHUNK + threadIdx.x;
        #pragma unroll
        for (int i = 0; i < SC_EPT; ++i) {
            int e = e0 + i * SC_THREADS;
            if (e < N_EDGES) atomicAdd(&lh[ei[e] >> 8], 1);
        }
        __syncthreads();
        int* row = partial + (size_t)blockIdx.x * NB;
        for (int i = threadIdx.x; i < NB; i += 256) row[i] = lh[i];
    }
}

// ---------------- parallel column scan: per-(block,bucket) bases ----------
__global__ __launch_bounds__(256) void scan_cols(int* __restrict__ partial,
                                                 int* __restrict__ btot) {
    __shared__ int s[256];
    const int b = blockIdx.x;
    const int t = threadIdx.x;
    const int v = (t < SC_BLOCKS) ? partial[(size_t)t * NB + b] : 0;
    s[t] = v;
    __syncthreads();
    for (int d2 = 1; d2 < 256; d2 <<= 1) {
        int u = (t >= d2) ? s[t - d2] : 0;
        __syncthreads();
        s[t] += u;
        __syncthreads();
    }
    if (t < SC_BLOCKS) partial[(size_t)t * NB + b] = s[t] - v;
    if (t == 255) btot[b] = s[255];
}

// ---------------- single-pass scatter into bucket runs ----------------
// Computes bucket offsets from btot in LDS (no scan_tops kernel).
// pack: hi32 = col(16b) | r8<<16 ; lo32 = f32 weight bits
__global__ __launch_bounds__(SC_THREADS) void edge_scatter(const int* __restrict__ ei,
                                                           const float* __restrict__ ew,
                                                           const int* __restrict__ partial,
                                                           const int* __restrict__ btot,
                                                           ull* __restrict__ packed) {
    __shared__ int sb[256];
    __shared__ int lbase[NB];
    __shared__ int lcur[NB];
    const int t = threadIdx.x;
    const int bv = (t < NB) ? btot[t] : 0;
    sb[t] = bv;
    __syncthreads();
    for (int d2 = 1; d2 < 256; d2 <<= 1) {
        int u = (t >= d2) ? sb[t - d2] : 0;
        __syncthreads();
        sb[t] += u;
        __syncthreads();
    }
    const int* row = partial + (size_t)blockIdx.x * NB;
    if (t < NB) {
        lbase[t] = (sb[t] - bv) + row[t];   // boffs[t] + per-block base
        lcur[t]  = 0;
    }
    __syncthreads();
    const int e0 = blockIdx.x * SC_CHUNK + t;
    #pragma unroll
    for (int i = 0; i < SC_EPT; ++i) {
        const int e = e0 + i * SC_THREADS;
        if (e < N_EDGES) {
            const int   r = ei[e];
            const int   c = ei[N_EDGES + e];
            const float w = ew[e];
            const int   b = r >> 8;
            const int   lpos = atomicAdd(&lcur[b], 1);
            const unsigned hi = (unsigned)c | ((unsigned)(r & 255) << 16);
            packed[lbase[b] + lpos] = ((ull)hi << 32) | (ull)(unsigned)__float_as_uint(w);
        }
    }
}

// ---------------- within-bucket node sort + CSR offsets + 4B compaction ----
__global__ __launch_bounds__(NS_THREADS) void node_sort(const int* __restrict__ btot,
                                                        int* __restrict__ offs,
                                                        const ull* __restrict__ packed,
                                                        unsigned* __restrict__ cedges) {
    __shared__ int cur[256];
    __shared__ int sc[256];
    __shared__ int sBase, sEnd;
    const int b = blockIdx.x;
    const int t = threadIdx.x;

    // bucket offsets from btot (replaces scan_tops)
    const int bv = (t < NB) ? btot[t] : 0;
    sc[t] = bv;
    __syncthreads();
    for (int d2 = 1; d2 < 256; d2 <<= 1) {
        int u = (t >= d2) ? sc[t - d2] : 0;
        __syncthreads();
        sc[t] += u;
        __syncthreads();
    }
    if (t == b) { sBase = sc[t] - bv; sEnd = sc[t]; }
    __syncthreads();
    const int s = sBase;
    const int e = sEnd;

    ull st[NS_EPT];
    #pragma unroll
    for (int i = 0; i < NS_EPT; ++i) {
        const int idx = s + t + i * NS_THREADS;
        st[i] = (idx < e) ? packed[idx] : ~0ull;   // sentinel
    }
    cur[t] = 0;
    __syncthreads();
    #pragma unroll
    for (int i = 0; i < NS_EPT; ++i) {
        if (st[i] != ~0ull) atomicAdd(&cur[(int)((st[i] >> 48) & 0xff)], 1);
    }
    __syncthreads();
    const int v = cur[t];
    sc[t] = v;
    __syncthreads();
    for (int d2 = 1; d2 < 256; d2 <<= 1) {
        int u = (t >= d2) ? sc[t - d2] : 0;
        __syncthreads();
        sc[t] += u;
        __syncthreads();
    }
    const int excl = sc[t] - v;
    const int n = b * 256 + t;
    if (n < N_NODES) offs[n] = s + excl;
    if (b == 0 && t == 0) offs[N_NODES] = N_EDGES;
    cur[t] = excl;          // per-node cursor
    __syncthreads();
    #pragma unroll
    for (int i = 0; i < NS_EPT; ++i) {
        if (st[i] != ~0ull) {
            const int r8  = (int)((st[i] >> 48) & 0xff);
            const int pos = atomicAdd(&cur[r8], 1);
            const unsigned hi  = (unsigned)(st[i] >> 32);
            const unsigned col = hi & 0xffffu;
            const unsigned wbf = f2bf(__uint_as_float((unsigned)st[i]));
            cedges[s + pos] = (col << 16) | wbf;
        }
    }
}

// ---------------- half-wave-per-node aggregation (bf16, 8 chains) --------
// Writes packed-bf16 mean to meanh (one word per lane).
__global__ __launch_bounds__(256) void sage_aggregate(const unsigned* __restrict__ xh,
                                                      const int* __restrict__ offs,
                                                      const unsigned* __restrict__ cedges,
                                                      unsigned* __restrict__ meanh) {
    const int n = (blockIdx.x * 256 + threadIdx.x) >> 5;   // half-wave id
    if (n >= N_NODES) return;
    const int fp = threadIdx.x & 31;
    const int s = offs[n];
    const int t = offs[n + 1];

    float a0x = 0.f, a0y = 0.f, a1x = 0.f, a1y = 0.f;
    float a2x = 0.f, a2y = 0.f, a3x = 0.f, a3y = 0.f;
    float a4x = 0.f, a4y = 0.f, a5x = 0.f, a5y = 0.f;
    float a6x = 0.f, a6y = 0.f, a7x = 0.f, a7y = 0.f;
    int e = s;
    for (; e + 7 < t; e += 8) {
        const unsigned c0 = cedges[e],     c1 = cedges[e + 1];
        const unsigned c2 = cedges[e + 2], c3 = cedges[e + 3];
        const unsigned c4 = cedges[e + 4], c5 = cedges[e + 5];
        const unsigned c6 = cedges[e + 6], c7 = cedges[e + 7];
        const unsigned v0 = xh[(c0 >> 16) * (D / 2) + fp];
        const unsigned v1 = xh[(c1 >> 16) * (D / 2) + fp];
        const unsigned v2 = xh[(c2 >> 16) * (D / 2) + fp];
        const unsigned v3 = xh[(c3 >> 16) * (D / 2) + fp];
        const unsigned v4 = xh[(c4 >> 16) * (D / 2) + fp];
        const unsigned v5 = xh[(c5 >> 16) * (D / 2) + fp];
        const unsigned v6 = xh[(c6 >> 16) * (D / 2) + fp];
        const unsigned v7 = xh[(c7 >> 16) * (D / 2) + fp];
        const float w0 = bf2f(c0 & 0xffffu), w1 = bf2f(c1 & 0xffffu);
        const float w2 = bf2f(c2 & 0xffffu), w3 = bf2f(c3 & 0xffffu);
        const float w4 = bf2f(c4 & 0xffffu), w5 = bf2f(c5 & 0xffffu);
        const float w6 = bf2f(c6 & 0xffffu), w7 = bf2f(c7 & 0xffffu);
        a0x = fmaf(__uint_as_float(v0 << 16),         w0, a0x);
        a0y = fmaf(__uint_as_float(v0 & 0xffff0000u), w0, a0y);
        a1x = fmaf(__uint_as_float(v1 << 16),         w1, a1x);
        a1y = fmaf(__uint_as_float(v1 & 0xffff0000u), w1, a1y);
        a2x = fmaf(__uint_as_float(v2 << 16),         w2, a2x);
        a2y = fmaf(__uint_as_float(v2 & 0xffff0000u), w2, a2y);
        a3x = fmaf(__uint_as_float(v3 << 16),         w3, a3x);
        a3y = fmaf(__uint_as_float(v3 & 0xffff0000u), w3, a3y);
        a4x = fmaf(__uint_as_float(v4 << 16),         w4, a4x);
        a4y = fmaf(__uint_as_float(v4 & 0xffff0000u), w4, a4y);
        a5x = fmaf(__uint_as_float(v5 << 16),         w5, a5x);
        a5y = fmaf(__uint_as_float(v5 & 0xffff0000u), w5, a5y);
        a6x = fmaf(__uint_as_float(v6 << 16),         w6, a6x);
        a6y = fmaf(__uint_as_float(v6 & 0xffff0000u), w6, a6y);
        a7x = fmaf(__uint_as_float(v7 << 16),         w7, a7x);
        a7y = fmaf(__uint_as_float(v7 & 0xffff0000u), w7, a7y);
    }
    for (; e + 3 < t; e += 4) {
        const unsigned c0 = cedges[e],     c1 = cedges[e + 1];
        const unsigned c2 = cedges[e + 2], c3 = cedges[e + 3];
        const unsigned v0 = xh[(c0 >> 16) * (D / 2) + fp];
        const unsigned v1 = xh[(c1 >> 16) * (D / 2) + fp];
        const unsigned v2 = xh[(c2 >> 16) * (D / 2) + fp];
        const unsigned v3 = xh[(c3 >> 16) * (D / 2) + fp];
        const float w0 = bf2f(c0 & 0xffffu), w1 = bf2f(c1 & 0xffffu);
        const float w2 = bf2f(c2 & 0xffffu), w3 = bf2f(c3 & 0xffffu);
        a0x = fmaf(__uint_as_float(v0 << 16),         w0, a0x);
        a0y = fmaf(__uint_as_float(v0 & 0xffff0000u), w0, a0y);
        a1x = fmaf(__uint_as_float(v1 << 16),         w1, a1x);
        a1y = fmaf(__uint_as_float(v1 & 0xffff0000u), w1, a1y);
        a2x = fmaf(__uint_as_float(v2 << 16),         w2, a2x);
        a2y = fmaf(__uint_as_float(v2 & 0xffff0000u), w2, a2y);
        a3x = fmaf(__uint_as_float(v3 << 16),         w3, a3x);
        a3y = fmaf(__uint_as_float(v3 & 0xffff0000u), w3, a3y);
    }
    for (; e < t; ++e) {
        const unsigned c = cedges[e];
        const unsigned v = xh[(c >> 16) * (D / 2) + fp];
        const float w = bf2f(c & 0xffffu);
        a0x = fmaf(__uint_as_float(v << 16),         w, a0x);
        a0y = fmaf(__uint_as_float(v & 0xffff0000u), w, a0y);
    }
    const float inv = 1.0f / fmaxf((float)(t - s), 1.0f);
    const float mx = (((a0x + a1x) + (a2x + a3x)) + ((a4x + a5x) + (a6x + a7x))) * inv;
    const float my = (((a0y + a1y) + (a2y + a3y)) + ((a4y + a5y) + (a6y + a7y))) * inv;
    meanh[n * (D / 2) + fp] = f2bf(mx) | (f2bf(my) << 16);
}

// ---------------- projection (bf16 feat sources, single out write) --------
__global__ __launch_bounds__(256) void sage_project(const unsigned* __restrict__ xh,
                                                    const unsigned* __restrict__ meanh,
                                                    const float* __restrict__ skern,
                                                    const float* __restrict__ nkern,
                                                    const float* __restrict__ bias,
                                                    float* __restrict__ out) {
    const int tg = threadIdx.x >> 7;
    const int j  = threadIdx.x & 127;
    const int jj = j & (D - 1);
    const float* K = (j < D) ? skern : nkern;

    float kcol[D];
    #pragma unroll
    for (int k = 0; k < D; ++k) kcol[k] = K[k * D + jj];
    const float bj = bias[j];
    const int base = (j < D) ? 0 : D;

    __shared__ float feat[2][UNITS];

    for (int n = blockIdx.x * 2 + tg; n < N_NODES; n += gridDim.x * 2) {
        if (j < 32) {
            const unsigned w = xh[n * (D / 2) + j];
            feat[tg][2 * j]     = bf2f(w & 0xffffu);
            feat[tg][2 * j + 1] = __uint_as_float(w & 0xffff0000u);
        } else if (j >= 64 && j < 96) {
            const unsigned w = meanh[n * (D / 2) + (j - 64)];
            feat[tg][64 + 2 * (j - 64)]     = bf2f(w & 0xffffu);
            feat[tg][64 + 2 * (j - 64) + 1] = __uint_as_float(w & 0xffff0000u);
        }
        __syncthreads();
        float acc2 = 0.0f;
        #pragma unroll
        for (int k = 0; k < D; ++k) acc2 += feat[tg][base + k] * kcol[k];
        acc2 += bj;
        out[n * UNITS + j] = fmaxf(acc2, 0.0f);
        __syncthreads();
    }
}

extern "C" void kernel_launch(void* const* d_in, const int* in_sizes, int n_in,
                              void* d_out, int out_size, void* d_ws, size_t ws_size,
                              hipStream_t stream) {
    const float* x     = (const float*)d_in[0];
    const int*   ei    = (const int*)  d_in[1];
    const float* ew    = (const float*)d_in[2];
    const float* skern = (const float*)d_in[3];
    const float* nkern = (const float*)d_in[4];
    const float* bias  = (const float*)d_in[5];
    float* out = (float*)d_out;

    auto align256 = [](size_t v) { return (v + 255) & ~size_t(255); };
    const size_t szM  = align256((size_t)SC_BLOCKS * NB * sizeof(int));   // partials matrix
    const size_t szT  = align256((size_t)NB * sizeof(int));               // bucket totals
    const size_t szNO = align256((size_t)(N_NODES + 1) * sizeof(int));
    const size_t szP  = align256((size_t)N_EDGES * sizeof(ull));
    const size_t szC  = align256((size_t)N_EDGES * sizeof(unsigned));
    const size_t szX  = align256((size_t)N_NODES * (D / 2) * sizeof(unsigned));

    char* w = (char*)d_ws;
    int*      partial = (int*)w;
    int*      btot    = (int*)(w + szM);
    int*      offs    = (int*)(w + szM + szT);
    ull*      packed  = (ull*)(w + szM + szT + szNO);
    unsigned* cedges  = (unsigned*)(w + szM + szT + szNO + szP);
    unsigned* xh      = (unsigned*)(w + szM + szT + szNO + szP + szC);
    unsigned* meanh   = (unsigned*)(w + szM + szT + szNO + szP + szC + szX);
    (void)ws_size; (void)in_sizes; (void)n_in; (void)out_size;

    prep          <<<PREP_BLOCKS, 256, 0, stream>>>(x, xh, ei, partial);
    scan_cols     <<<NB, 256, 0, stream>>>(partial, btot);
    edge_scatter  <<<SC_BLOCKS, SC_THREADS, 0, stream>>>(ei, ew, partial, btot, packed);
    node_sort     <<<NB, NS_THREADS, 0, stream>>>(btot, offs, packed, cedges);
    sage_aggregate<<<(N_NODES * 32 + 255) / 256, 256, 0, stream>>>(xh, offs, cedges, meanh);
    sage_project  <<<2048, 256, 0, stream>>>(xh, meanh, skern, nkern, bias, out);
}

// Round 13
// 67.827 us; speedup vs baseline: 2.0182x; 1.2101x over previous
//
#include <hip/hip_runtime.h>

// MeanGraphSage: h = relu(concat(x @ Ws, mean_neighbors @ Wn) + bias)
// N=50000 nodes, E=800000 edges, D=64 in-feats, 128 out (64+64 concat).
//
// Round 13 (from 82.1us r12): sage_project was LDS-broadcast + VALU bound
// (409.6M lane ds_reads ~= 25K LDS instrs/CU ~= 15-20us). Replace with an
// MFMA projection: wave computes a 16-node x 128-output tile via 16x
// mfma_f32_16x16x32_bf16; A frags load directly from the bf16-packed
// xh/meanh rows (16B per lane per K-half); B frags = both kernels
// bf16-packed in registers (preloaded once per wave). No LDS, no barriers.
// Rest of the pipeline byte-identical to round 12.

typedef unsigned long long ull;
typedef __attribute__((ext_vector_type(8))) short bf16x8;
typedef __attribute__((ext_vector_type(4))) float f32x4;

constexpr int N_NODES = 50000;
constexpr int N_EDGES = 800000;
constexpr int D = 64;
constexpr int UNITS = 128;
constexpr int NB = (N_NODES + 255) / 256;           // 196 buckets of 256 nodes
constexpr int SC_EPT = 16;                           // scatter: edges/thread
constexpr int SC_THREADS = 256;
constexpr int SC_CHUNK = SC_EPT * SC_THREADS;        // 4096
constexpr int SC_BLOCKS = (N_EDGES + SC_CHUNK - 1) / SC_CHUNK;  // 196
constexpr int NS_THREADS = 256;
constexpr int NS_EPT = 24;                           // bucket capacity 6144
constexpr int PREP_BLOCKS = 2048;
constexpr int NTILES = N_NODES / 16;                 // 3125 (exact)
constexpr int PJ_BLOCKS = (NTILES + 3) / 4;          // 782 (4 waves/block)

__device__ __forceinline__ unsigned f2bf(float f) {   // RNE f32 -> bf16 bits
    unsigned u = __float_as_uint(f);
    return (u + 0x7fffu + ((u >> 16) & 1u)) >> 16;
}
__device__ __forceinline__ float bf2f(unsigned b) {   // bf16 bits -> f32
    return __uint_as_float(b << 16);
}

// ---------------- prep: x->bf16 table + bucket histogram ----------------
__global__ __launch_bounds__(256) void prep(const float* __restrict__ x,
                                            unsigned* __restrict__ xh,
                                            const int* __restrict__ ei,
                                            int* __restrict__ partial) {
    constexpr int XW = N_NODES * (D / 2);   // 1.6M packed words
    for (int i = blockIdx.x * 256 + threadIdx.x; i < XW; i += PREP_BLOCKS * 256) {
        const float2 v = ((const float2*)x)[i];
        xh[i] = f2bf(v.x) | (f2bf(v.y) << 16);
    }
    if (blockIdx.x < SC_BLOCKS) {
        __shared__ int lh[NB];
        for (int i = threadIdx.x; i < NB; i += 256) lh[i] = 0;
        __syncthreads();
        const int e0 = blockIdx.x * SC_CHUNK + threadIdx.x;
        #pragma unroll
        for (int i = 0; i < SC_EPT; ++i) {
            int e = e0 + i * SC_THREADS;
            if (e < N_EDGES) atomicAdd(&lh[ei[e] >> 8], 1);
        }
        __syncthreads();
        int* row = partial + (size_t)blockIdx.x * NB;
        for (int i = threadIdx.x; i < NB; i += 256) row[i] = lh[i];
    }
}

// ---------------- parallel column scan: per-(block,bucket) bases ----------
__global__ __launch_bounds__(256) void scan_cols(int* __restrict__ partial,
                                                 int* __restrict__ btot) {
    __shared__ int s[256];
    const int b = blockIdx.x;
    const int t = threadIdx.x;
    const int v = (t < SC_BLOCKS) ? partial[(size_t)t * NB + b] : 0;
    s[t] = v;
    __syncthreads();
    for (int d2 = 1; d2 < 256; d2 <<= 1) {
        int u = (t >= d2) ? s[t - d2] : 0;
        __syncthreads();
        s[t] += u;
        __syncthreads();
    }
    if (t < SC_BLOCKS) partial[(size_t)t * NB + b] = s[t] - v;
    if (t == 255) btot[b] = s[255];
}

// ---------------- single-pass scatter into bucket runs ----------------
// pack: hi32 = col(16b) | r8<<16 ; lo32 = f32 weight bits
__global__ __launch_bounds__(SC_THREADS) void edge_scatter(const int* __restrict__ ei,
                                                           const float* __restrict__ ew,
                                                           const int* __restrict__ partial,
                                                           const int* __restrict__ btot,
                                                           ull* __restrict__ packed) {
    __shared__ int sb[256];
    __shared__ int lbase[NB];
    __shared__ int lcur[NB];
    const int t = threadIdx.x;
    const int bv = (t < NB) ? btot[t] : 0;
    sb[t] = bv;
    __syncthreads();
    for (int d2 = 1; d2 < 256; d2 <<= 1) {
        int u = (t >= d2) ? sb[t - d2] : 0;
        __syncthreads();
        sb[t] += u;
        __syncthreads();
    }
    const int* row = partial + (size_t)blockIdx.x * NB;
    if (t < NB) {
        lbase[t] = (sb[t] - bv) + row[t];   // boffs[t] + per-block base
        lcur[t]  = 0;
    }
    __syncthreads();
    const int e0 = blockIdx.x * SC_CHUNK + t;
    #pragma unroll
    for (int i = 0; i < SC_EPT; ++i) {
        const int e = e0 + i * SC_THREADS;
        if (e < N_EDGES) {
            const int   r = ei[e];
            const int   c = ei[N_EDGES + e];
            const float w = ew[e];
            const int   b = r >> 8;
            const int   lpos = atomicAdd(&lcur[b], 1);
            const unsigned hi = (unsigned)c | ((unsigned)(r & 255) << 16);
            packed[lbase[b] + lpos] = ((ull)hi << 32) | (ull)(unsigned)__float_as_uint(w);
        }
    }
}

// ---------------- within-bucket node sort + CSR offsets + 4B compaction ----
__global__ __launch_bounds__(NS_THREADS) void node_sort(const int* __restrict__ btot,
                                                        int* __restrict__ offs,
                                                        const ull* __restrict__ packed,
                                                        unsigned* __restrict__ cedges) {
    __shared__ int cur[256];
    __shared__ int sc[256];
    __shared__ int sBase, sEnd;
    const int b = blockIdx.x;
    const int t = threadIdx.x;

    const int bv = (t < NB) ? btot[t] : 0;
    sc[t] = bv;
    __syncthreads();
    for (int d2 = 1; d2 < 256; d2 <<= 1) {
        int u = (t >= d2) ? sc[t - d2] : 0;
        __syncthreads();
        sc[t] += u;
        __syncthreads();
    }
    if (t == b) { sBase = sc[t] - bv; sEnd = sc[t]; }
    __syncthreads();
    const int s = sBase;
    const int e = sEnd;

    ull st[NS_EPT];
    #pragma unroll
    for (int i = 0; i < NS_EPT; ++i) {
        const int idx = s + t + i * NS_THREADS;
        st[i] = (idx < e) ? packed[idx] : ~0ull;   // sentinel
    }
    cur[t] = 0;
    __syncthreads();
    #pragma unroll
    for (int i = 0; i < NS_EPT; ++i) {
        if (st[i] != ~0ull) atomicAdd(&cur[(int)((st[i] >> 48) & 0xff)], 1);
    }
    __syncthreads();
    const int v = cur[t];
    sc[t] = v;
    __syncthreads();
    for (int d2 = 1; d2 < 256; d2 <<= 1) {
        int u = (t >= d2) ? sc[t - d2] : 0;
        __syncthreads();
        sc[t] += u;
        __syncthreads();
    }
    const int excl = sc[t] - v;
    const int n = b * 256 + t;
    if (n < N_NODES) offs[n] = s + excl;
    if (b == 0 && t == 0) offs[N_NODES] = N_EDGES;
    cur[t] = excl;          // per-node cursor
    __syncthreads();
    #pragma unroll
    for (int i = 0; i < NS_EPT; ++i) {
        if (st[i] != ~0ull) {
            const int r8  = (int)((st[i] >> 48) & 0xff);
            const int pos = atomicAdd(&cur[r8], 1);
            const unsigned hi  = (unsigned)(st[i] >> 32);
            const unsigned col = hi & 0xffffu;
            const unsigned wbf = f2bf(__uint_as_float((unsigned)st[i]));
            cedges[s + pos] = (col << 16) | wbf;
        }
    }
}

// ---------------- half-wave-per-node aggregation (bf16, 8 chains) --------
__global__ __launch_bounds__(256) void sage_aggregate(const unsigned* __restrict__ xh,
                                                      const int* __restrict__ offs,
                                                      const unsigned* __restrict__ cedges,
                                                      unsigned* __restrict__ meanh) {
    const int n = (blockIdx.x * 256 + threadIdx.x) >> 5;   // half-wave id
    if (n >= N_NODES) return;
    const int fp = threadIdx.x & 31;
    const int s = offs[n];
    const int t = offs[n + 1];

    float a0x = 0.f, a0y = 0.f, a1x = 0.f, a1y = 0.f;
    float a2x = 0.f, a2y = 0.f, a3x = 0.f, a3y = 0.f;
    float a4x = 0.f, a4y = 0.f, a5x = 0.f, a5y = 0.f;
    float a6x = 0.f, a6y = 0.f, a7x = 0.f, a7y = 0.f;
    int e = s;
    for (; e + 7 < t; e += 8) {
        const unsigned c0 = cedges[e],     c1 = cedges[e + 1];
        const unsigned c2 = cedges[e + 2], c3 = cedges[e + 3];
        const unsigned c4 = cedges[e + 4], c5 = cedges[e + 5];
        const unsigned c6 = cedges[e + 6], c7 = cedges[e + 7];
        const unsigned v0 = xh[(c0 >> 16) * (D / 2) + fp];
        const unsigned v1 = xh[(c1 >> 16) * (D / 2) + fp];
        const unsigned v2 = xh[(c2 >> 16) * (D / 2) + fp];
        const unsigned v3 = xh[(c3 >> 16) * (D / 2) + fp];
        const unsigned v4 = xh[(c4 >> 16) * (D / 2) + fp];
        const unsigned v5 = xh[(c5 >> 16) * (D / 2) + fp];
        const unsigned v6 = xh[(c6 >> 16) * (D / 2) + fp];
        const unsigned v7 = xh[(c7 >> 16) * (D / 2) + fp];
        const float w0 = bf2f(c0 & 0xffffu), w1 = bf2f(c1 & 0xffffu);
        const float w2 = bf2f(c2 & 0xffffu), w3 = bf2f(c3 & 0xffffu);
        const float w4 = bf2f(c4 & 0xffffu), w5 = bf2f(c5 & 0xffffu);
        const float w6 = bf2f(c6 & 0xffffu), w7 = bf2f(c7 & 0xffffu);
        a0x = fmaf(__uint_as_float(v0 << 16),         w0, a0x);
        a0y = fmaf(__uint_as_float(v0 & 0xffff0000u), w0, a0y);
        a1x = fmaf(__uint_as_float(v1 << 16),         w1, a1x);
        a1y = fmaf(__uint_as_float(v1 & 0xffff0000u), w1, a1y);
        a2x = fmaf(__uint_as_float(v2 << 16),         w2, a2x);
        a2y = fmaf(__uint_as_float(v2 & 0xffff0000u), w2, a2y);
        a3x = fmaf(__uint_as_float(v3 << 16),         w3, a3x);
        a3y = fmaf(__uint_as_float(v3 & 0xffff0000u), w3, a3y);
        a4x = fmaf(__uint_as_float(v4 << 16),         w4, a4x);
        a4y = fmaf(__uint_as_float(v4 & 0xffff0000u), w4, a4y);
        a5x = fmaf(__uint_as_float(v5 << 16),         w5, a5x);
        a5y = fmaf(__uint_as_float(v5 & 0xffff0000u), w5, a5y);
        a6x = fmaf(__uint_as_float(v6 << 16),         w6, a6x);
        a6y = fmaf(__uint_as_float(v6 & 0xffff0000u), w6, a6y);
        a7x = fmaf(__uint_as_float(v7 << 16),         w7, a7x);
        a7y = fmaf(__uint_as_float(v7 & 0xffff0000u), w7, a7y);
    }
    for (; e + 3 < t; e += 4) {
        const unsigned c0 = cedges[e],     c1 = cedges[e + 1];
        const unsigned c2 = cedges[e + 2], c3 = cedges[e + 3];
        const unsigned v0 = xh[(c0 >> 16) * (D / 2) + fp];
        const unsigned v1 = xh[(c1 >> 16) * (D / 2) + fp];
        const unsigned v2 = xh[(c2 >> 16) * (D / 2) + fp];
        const unsigned v3 = xh[(c3 >> 16) * (D / 2) + fp];
        const float w0 = bf2f(c0 & 0xffffu), w1 = bf2f(c1 & 0xffffu);
        const float w2 = bf2f(c2 & 0xffffu), w3 = bf2f(c3 & 0xffffu);
        a0x = fmaf(__uint_as_float(v0 << 16),         w0, a0x);
        a0y = fmaf(__uint_as_float(v0 & 0xffff0000u), w0, a0y);
        a1x = fmaf(__uint_as_float(v1 << 16),         w1, a1x);
        a1y = fmaf(__uint_as_float(v1 & 0xffff0000u), w1, a1y);
        a2x = fmaf(__uint_as_float(v2 << 16),         w2, a2x);
        a2y = fmaf(__uint_as_float(v2 & 0xffff0000u), w2, a2y);
        a3x = fmaf(__uint_as_float(v3 << 16),         w3, a3x);
        a3y = fmaf(__uint_as_float(v3 & 0xffff0000u), w3, a3y);
    }
    for (; e < t; ++e) {
        const unsigned c = cedges[e];
        const unsigned v = xh[(c >> 16) * (D / 2) + fp];
        const float w = bf2f(c & 0xffffu);
        a0x = fmaf(__uint_as_float(v << 16),         w, a0x);
        a0y = fmaf(__uint_as_float(v & 0xffff0000u), w, a0y);
    }
    const float inv = 1.0f / fmaxf((float)(t - s), 1.0f);
    const float mx = (((a0x + a1x) + (a2x + a3x)) + ((a4x + a5x) + (a6x + a7x))) * inv;
    const float my = (((a0y + a1y) + (a2y + a3y)) + ((a4y + a5y) + (a6y + a7y))) * inv;
    meanh[n * (D / 2) + fp] = f2bf(mx) | (f2bf(my) << 16);
}

// ---------------- MFMA projection: 16-node x 128-output tile per wave -----
// A frag (16x16x32 bf16): lane holds A[l&15][8*(l>>4)+j] -> one 16B load per
// K-half straight from the packed bf16 row. B frag: B[k][col], col=l&15,
// k=8*(l>>4)+j. C/D: col=l&15, row=(l>>4)*4+reg [HW-verified mapping].
__global__ __launch_bounds__(256) void sage_project(const unsigned* __restrict__ xh,
                                                    const unsigned* __restrict__ meanh,
                                                    const float* __restrict__ skern,
                                                    const float* __restrict__ nkern,
                                                    const float* __restrict__ bias,
                                                    float* __restrict__ out) {
    const int lane = threadIdx.x & 63;
    const int wid  = (blockIdx.x * 256 + threadIdx.x) >> 6;  // global wave id
    const int r16  = lane & 15;
    const int g    = lane >> 4;

    // B fragments: 8 col-tiles (ct 0..3 self, 4..7 neighbor) x 2 K-halves
    bf16x8 bfrag[16];
    #pragma unroll
    for (int ct = 0; ct < 8; ++ct) {
        const float* K = (ct < 4) ? skern : nkern;
        const int col = (ct & 3) * 16 + r16;
        #pragma unroll
        for (int kh = 0; kh < 2; ++kh) {
            bf16x8 f;
            #pragma unroll
            for (int j = 0; j < 8; ++j) {
                const int k = kh * 32 + 8 * g + j;
                f[j] = (short)f2bf(K[k * 64 + col]);
            }
            bfrag[ct * 2 + kh] = f;
        }
    }

    if (wid >= NTILES) return;
    const int n0 = wid * 16;

    const unsigned* xrow = xh    + (size_t)(n0 + r16) * (D / 2);
    const unsigned* mrow = meanh + (size_t)(n0 + r16) * (D / 2);
    const bf16x8 aS0 = *(const bf16x8*)(xrow + 4 * g);        // k 0..31
    const bf16x8 aS1 = *(const bf16x8*)(xrow + 16 + 4 * g);   // k 32..63
    const bf16x8 aN0 = *(const bf16x8*)(mrow + 4 * g);
    const bf16x8 aN1 = *(const bf16x8*)(mrow + 16 + 4 * g);

    f32x4 acc[8];
    #pragma unroll
    for (int ct = 0; ct < 8; ++ct) {
        f32x4 c = {0.f, 0.f, 0.f, 0.f};
        c = __builtin_amdgcn_mfma_f32_16x16x32_bf16(ct < 4 ? aS0 : aN0, bfrag[ct * 2 + 0], c, 0, 0, 0);
        c = __builtin_amdgcn_mfma_f32_16x16x32_bf16(ct < 4 ? aS1 : aN1, bfrag[ct * 2 + 1], c, 0, 0, 0);
        acc[ct] = c;
    }

    #pragma unroll
    for (int ct = 0; ct < 8; ++ct) {
        const int col = (ct < 4 ? 0 : 64) + (ct & 3) * 16 + r16;
        const float bj = bias[col];
        #pragma unroll
        for (int r = 0; r < 4; ++r) {
            const int node = n0 + 4 * g + r;
            out[(size_t)node * UNITS + col] = fmaxf(acc[ct][r] + bj, 0.0f);
        }
    }
}

extern "C" void kernel_launch(void* const* d_in, const int* in_sizes, int n_in,
                              void* d_out, int out_size, void* d_ws, size_t ws_size,
                              hipStream_t stream) {
    const float* x     = (const float*)d_in[0];
    const int*   ei    = (const int*)  d_in[1];
    const float* ew    = (const float*)d_in[2];
    const float* skern = (const float*)d_in[3];
    const float* nkern = (const float*)d_in[4];
    const float* bias  = (const float*)d_in[5];
    float* out = (float*)d_out;

    auto align256 = [](size_t v) { return (v + 255) & ~size_t(255); };
    const size_t szM  = align256((size_t)SC_BLOCKS * NB * sizeof(int));   // partials matrix
    const size_t szT  = align256((size_t)NB * sizeof(int));               // bucket totals
    const size_t szNO = align256((size_t)(N_NODES + 1) * sizeof(int));
    const size_t szP  = align256((size_t)N_EDGES * sizeof(ull));
    const size_t szC  = align256((size_t)N_EDGES * sizeof(unsigned));
    const size_t szX  = align256((size_t)N_NODES * (D / 2) * sizeof(unsigned));

    char* w = (char*)d_ws;
    int*      partial = (int*)w;
    int*      btot    = (int*)(w + szM);
    int*      offs    = (int*)(w + szM + szT);
    ull*      packed  = (ull*)(w + szM + szT + szNO);
    unsigned* cedges  = (unsigned*)(w + szM + szT + szNO + szP);
    unsigned* xh      = (unsigned*)(w + szM + szT + szNO + szP + szC);
    unsigned* meanh   = (unsigned*)(w + szM + szT + szNO + szP + szC + szX);
    (void)ws_size; (void)in_sizes; (void)n_in; (void)out_size;

    prep          <<<PREP_BLOCKS, 256, 0, stream>>>(x, xh, ei, partial);
    scan_cols     <<<NB, 256, 0, stream>>>(partial, btot);
    edge_scatter  <<<SC_BLOCKS, SC_THREADS, 0, stream>>>(ei, ew, partial, btot, packed);
    node_sort     <<<NB, NS_THREADS, 0, stream>>>(btot, offs, packed, cedges);
    sage_aggregate<<<(N_NODES * 32 + 255) / 256, 256, 0, stream>>>(xh, offs, cedges, meanh);
    sage_project  <<<PJ_BLOCKS, 256, 0, stream>>>(xh, meanh, skern, nkern, bias, out);
}

// Round 14
// 64.730 us; speedup vs baseline: 2.1148x; 1.0478x over previous
//
#include <hip/hip_runtime.h>

// MeanGraphSage: h = relu(concat(x @ Ws, mean_neighbors @ Wn) + bias)
// N=50000 nodes, E=800000 edges, D=64 in-feats, 128 out (64+64 concat).
//
// Round 14 (from 67.8us r13): aggregate is VMEM-instruction-rate bound
// (1 gather instr/edge, 4B/lane). Widen to dwordx4: lane fetches 16B, 8
// lanes cover the 128B row -> ONE gather instr serves FOUR edges (4x fewer
// VMEM instrs). Lane l: edge g+(l>>3), word-quad l&7. Two chains = 8
// edges/iter. Epilogue: chain-combine + shfl_xor(8,16) + lanes0-7 store a
// uint4 (coalesced 128B row). Tail predicated w=0, clamped index.
// Everything else byte-identical to round 13.

typedef unsigned long long ull;
typedef __attribute__((ext_vector_type(8))) short bf16x8;
typedef __attribute__((ext_vector_type(4))) float f32x4;

constexpr int N_NODES = 50000;
constexpr int N_EDGES = 800000;
constexpr int D = 64;
constexpr int UNITS = 128;
constexpr int NB = (N_NODES + 255) / 256;           // 196 buckets of 256 nodes
constexpr int SC_EPT = 16;                           // scatter: edges/thread
constexpr int SC_THREADS = 256;
constexpr int SC_CHUNK = SC_EPT * SC_THREADS;        // 4096
constexpr int SC_BLOCKS = (N_EDGES + SC_CHUNK - 1) / SC_CHUNK;  // 196
constexpr int NS_THREADS = 256;
constexpr int NS_EPT = 24;                           // bucket capacity 6144
constexpr int PREP_BLOCKS = 2048;
constexpr int NTILES = N_NODES / 16;                 // 3125 (exact)
constexpr int PJ_BLOCKS = (NTILES + 3) / 4;          // 782 (4 waves/block)

__device__ __forceinline__ unsigned f2bf(float f) {   // RNE f32 -> bf16 bits
    unsigned u = __float_as_uint(f);
    return (u + 0x7fffu + ((u >> 16) & 1u)) >> 16;
}
__device__ __forceinline__ float bf2f(unsigned b) {   // bf16 bits -> f32
    return __uint_as_float(b << 16);
}

// ---------------- prep: x->bf16 table + bucket histogram ----------------
__global__ __launch_bounds__(256) void prep(const float* __restrict__ x,
                                            unsigned* __restrict__ xh,
                                            const int* __restrict__ ei,
                                            int* __restrict__ partial) {
    constexpr int XW = N_NODES * (D / 2);   // 1.6M packed words
    for (int i = blockIdx.x * 256 + threadIdx.x; i < XW; i += PREP_BLOCKS * 256) {
        const float2 v = ((const float2*)x)[i];
        xh[i] = f2bf(v.x) | (f2bf(v.y) << 16);
    }
    if (blockIdx.x < SC_BLOCKS) {
        __shared__ int lh[NB];
        for (int i = threadIdx.x; i < NB; i += 256) lh[i] = 0;
        __syncthreads();
        const int e0 = blockIdx.x * SC_CHUNK + threadIdx.x;
        #pragma unroll
        for (int i = 0; i < SC_EPT; ++i) {
            int e = e0 + i * SC_THREADS;
            if (e < N_EDGES) atomicAdd(&lh[ei[e] >> 8], 1);
        }
        __syncthreads();
        int* row = partial + (size_t)blockIdx.x * NB;
        for (int i = threadIdx.x; i < NB; i += 256) row[i] = lh[i];
    }
}

// ---------------- parallel column scan: per-(block,bucket) bases ----------
__global__ __launch_bounds__(256) void scan_cols(int* __restrict__ partial,
                                                 int* __restrict__ btot) {
    __shared__ int s[256];
    const int b = blockIdx.x;
    const int t = threadIdx.x;
    const int v = (t < SC_BLOCKS) ? partial[(size_t)t * NB + b] : 0;
    s[t] = v;
    __syncthreads();
    for (int d2 = 1; d2 < 256; d2 <<= 1) {
        int u = (t >= d2) ? s[t - d2] : 0;
        __syncthreads();
        s[t] += u;
        __syncthreads();
    }
    if (t < SC_BLOCKS) partial[(size_t)t * NB + b] = s[t] - v;
    if (t == 255) btot[b] = s[255];
}

// ---------------- single-pass scatter into bucket runs ----------------
// pack: hi32 = col(16b) | r8<<16 ; lo32 = f32 weight bits
__global__ __launch_bounds__(SC_THREADS) void edge_scatter(const int* __restrict__ ei,
                                                           const float* __restrict__ ew,
                                                           const int* __restrict__ partial,
                                                           const int* __restrict__ btot,
                                                           ull* __restrict__ packed) {
    __shared__ int sb[256];
    __shared__ int lbase[NB];
    __shared__ int lcur[NB];
    const int t = threadIdx.x;
    const int bv = (t < NB) ? btot[t] : 0;
    sb[t] = bv;
    __syncthreads();
    for (int d2 = 1; d2 < 256; d2 <<= 1) {
        int u = (t >= d2) ? sb[t - d2] : 0;
        __syncthreads();
        sb[t] += u;
        __syncthreads();
    }
    const int* row = partial + (size_t)blockIdx.x * NB;
    if (t < NB) {
        lbase[t] = (sb[t] - bv) + row[t];   // boffs[t] + per-block base
        lcur[t]  = 0;
    }
    __syncthreads();
    const int e0 = blockIdx.x * SC_CHUNK + t;
    #pragma unroll
    for (int i = 0; i < SC_EPT; ++i) {
        const int e = e0 + i * SC_THREADS;
        if (e < N_EDGES) {
            const int   r = ei[e];
            const int   c = ei[N_EDGES + e];
            const float w = ew[e];
            const int   b = r >> 8;
            const int   lpos = atomicAdd(&lcur[b], 1);
            const unsigned hi = (unsigned)c | ((unsigned)(r & 255) << 16);
            packed[lbase[b] + lpos] = ((ull)hi << 32) | (ull)(unsigned)__float_as_uint(w);
        }
    }
}

// ---------------- within-bucket node sort + CSR offsets + 4B compaction ----
__global__ __launch_bounds__(NS_THREADS) void node_sort(const int* __restrict__ btot,
                                                        int* __restrict__ offs,
                                                        const ull* __restrict__ packed,
                                                        unsigned* __restrict__ cedges) {
    __shared__ int cur[256];
    __shared__ int sc[256];
    __shared__ int sBase, sEnd;
    const int b = blockIdx.x;
    const int t = threadIdx.x;

    const int bv = (t < NB) ? btot[t] : 0;
    sc[t] = bv;
    __syncthreads();
    for (int d2 = 1; d2 < 256; d2 <<= 1) {
        int u = (t >= d2) ? sc[t - d2] : 0;
        __syncthreads();
        sc[t] += u;
        __syncthreads();
    }
    if (t == b) { sBase = sc[t] - bv; sEnd = sc[t]; }
    __syncthreads();
    const int s = sBase;
    const int e = sEnd;

    ull st[NS_EPT];
    #pragma unroll
    for (int i = 0; i < NS_EPT; ++i) {
        const int idx = s + t + i * NS_THREADS;
        st[i] = (idx < e) ? packed[idx] : ~0ull;   // sentinel
    }
    cur[t] = 0;
    __syncthreads();
    #pragma unroll
    for (int i = 0; i < NS_EPT; ++i) {
        if (st[i] != ~0ull) atomicAdd(&cur[(int)((st[i] >> 48) & 0xff)], 1);
    }
    __syncthreads();
    const int v = cur[t];
    sc[t] = v;
    __syncthreads();
    for (int d2 = 1; d2 < 256; d2 <<= 1) {
        int u = (t >= d2) ? sc[t - d2] : 0;
        __syncthreads();
        sc[t] += u;
        __syncthreads();
    }
    const int excl = sc[t] - v;
    const int n = b * 256 + t;
    if (n < N_NODES) offs[n] = s + excl;
    if (b == 0 && t == 0) offs[N_NODES] = N_EDGES;
    cur[t] = excl;          // per-node cursor
    __syncthreads();
    #pragma unroll
    for (int i = 0; i < NS_EPT; ++i) {
        if (st[i] != ~0ull) {
            const int r8  = (int)((st[i] >> 48) & 0xff);
            const int pos = atomicAdd(&cur[r8], 1);
            const unsigned hi  = (unsigned)(st[i] >> 32);
            const unsigned col = hi & 0xffffu;
            const unsigned wbf = f2bf(__uint_as_float((unsigned)st[i]));
            cedges[s + pos] = (col << 16) | wbf;
        }
    }
}

// ---------------- half-wave-per-node aggregation (dwordx4 gathers) --------
// Lane l (of 32): edge subgroup eg=l>>3, word-quad wq=l&7. One dwordx4
// gather serves 4 edges (8 lanes x 16B = 128B row). Two chains = 8
// edges/iter. Reduce across subgroups via shfl_xor(8,16); lanes 0-7 store
// the packed-bf16 mean row as one uint4 each.
__global__ __launch_bounds__(256) void sage_aggregate(const unsigned* __restrict__ xh,
                                                      const int* __restrict__ offs,
                                                      const unsigned* __restrict__ cedges,
                                                      unsigned* __restrict__ meanh) {
    const int n = (blockIdx.x * 256 + threadIdx.x) >> 5;   // half-wave id = node
    if (n >= N_NODES) return;
    const int l32 = threadIdx.x & 31;
    const int eg  = l32 >> 3;
    const int wq  = l32 & 7;
    const int s = offs[n];
    const int t = offs[n + 1];

    float ax0 = 0.f, ay0 = 0.f, ax1 = 0.f, ay1 = 0.f;
    float ax2 = 0.f, ay2 = 0.f, ax3 = 0.f, ay3 = 0.f;
    float bx0 = 0.f, by0 = 0.f, bx1 = 0.f, by1 = 0.f;
    float bx2 = 0.f, by2 = 0.f, bx3 = 0.f, by3 = 0.f;

    if (t > s) {
        const int tm1 = t - 1;
        for (int g = s; g < t; g += 8) {
            const int eA = g + eg;
            const int eB = g + 4 + eg;
            const unsigned cA = cedges[min(eA, tm1)];
            const unsigned cB = cedges[min(eB, tm1)];
            const float wA = (eA < t) ? bf2f(cA & 0xffffu) : 0.0f;
            const float wB = (eB < t) ? bf2f(cB & 0xffffu) : 0.0f;
            const uint4 vA = *(const uint4*)(xh + (size_t)(cA >> 16) * (D / 2) + wq * 4);
            const uint4 vB = *(const uint4*)(xh + (size_t)(cB >> 16) * (D / 2) + wq * 4);
            ax0 = fmaf(__uint_as_float(vA.x << 16),         wA, ax0);
            ay0 = fmaf(__uint_as_float(vA.x & 0xffff0000u), wA, ay0);
            ax1 = fmaf(__uint_as_float(vA.y << 16),         wA, ax1);
            ay1 = fmaf(__uint_as_float(vA.y & 0xffff0000u), wA, ay1);
            ax2 = fmaf(__uint_as_float(vA.z << 16),         wA, ax2);
            ay2 = fmaf(__uint_as_float(vA.z & 0xffff0000u), wA, ay2);
            ax3 = fmaf(__uint_as_float(vA.w << 16),         wA, ax3);
            ay3 = fmaf(__uint_as_float(vA.w & 0xffff0000u), wA, ay3);
            bx0 = fmaf(__uint_as_float(vB.x << 16),         wB, bx0);
            by0 = fmaf(__uint_as_float(vB.x & 0xffff0000u), wB, by0);
            bx1 = fmaf(__uint_as_float(vB.y << 16),         wB, bx1);
            by1 = fmaf(__uint_as_float(vB.y & 0xffff0000u), wB, by1);
            bx2 = fmaf(__uint_as_float(vB.z << 16),         wB, bx2);
            by2 = fmaf(__uint_as_float(vB.z & 0xffff0000u), wB, by2);
            bx3 = fmaf(__uint_as_float(vB.w << 16),         wB, bx3);
            by3 = fmaf(__uint_as_float(vB.w & 0xffff0000u), wB, by3);
        }
    }
    // combine chains, then reduce the 4 edge-subgroups (lanes l, l^8, l^16, l^24)
    float sx0 = ax0 + bx0, sy0 = ay0 + by0;
    float sx1 = ax1 + bx1, sy1 = ay1 + by1;
    float sx2 = ax2 + bx2, sy2 = ay2 + by2;
    float sx3 = ax3 + bx3, sy3 = ay3 + by3;
    sx0 += __shfl_xor(sx0, 8);  sx0 += __shfl_xor(sx0, 16);
    sy0 += __shfl_xor(sy0, 8);  sy0 += __shfl_xor(sy0, 16);
    sx1 += __shfl_xor(sx1, 8);  sx1 += __shfl_xor(sx1, 16);
    sy1 += __shfl_xor(sy1, 8);  sy1 += __shfl_xor(sy1, 16);
    sx2 += __shfl_xor(sx2, 8);  sx2 += __shfl_xor(sx2, 16);
    sy2 += __shfl_xor(sy2, 8);  sy2 += __shfl_xor(sy2, 16);
    sx3 += __shfl_xor(sx3, 8);  sx3 += __shfl_xor(sx3, 16);
    sy3 += __shfl_xor(sy3, 8);  sy3 += __shfl_xor(sy3, 16);

    if (eg == 0) {   // lanes 0-7 of the half-wave
        const float inv = 1.0f / fmaxf((float)(t - s), 1.0f);
        uint4 r;
        r.x = f2bf(sx0 * inv) | (f2bf(sy0 * inv) << 16);
        r.y = f2bf(sx1 * inv) | (f2bf(sy1 * inv) << 16);
        r.z = f2bf(sx2 * inv) | (f2bf(sy2 * inv) << 16);
        r.w = f2bf(sx3 * inv) | (f2bf(sy3 * inv) << 16);
        *(uint4*)(meanh + (size_t)n * (D / 2) + wq * 4) = r;
    }
}

// ---------------- MFMA projection: 16-node x 128-output tile per wave -----
__global__ __launch_bounds__(256) void sage_project(const unsigned* __restrict__ xh,
                                                    const unsigned* __restrict__ meanh,
                                                    const float* __restrict__ skern,
                                                    const float* __restrict__ nkern,
                                                    const float* __restrict__ bias,
                                                    float* __restrict__ out) {
    const int lane = threadIdx.x & 63;
    const int wid  = (blockIdx.x * 256 + threadIdx.x) >> 6;  // global wave id
    const int r16  = lane & 15;
    const int g    = lane >> 4;

    bf16x8 bfrag[16];
    #pragma unroll
    for (int ct = 0; ct < 8; ++ct) {
        const float* K = (ct < 4) ? skern : nkern;
        const int col = (ct & 3) * 16 + r16;
        #pragma unroll
        for (int kh = 0; kh < 2; ++kh) {
            bf16x8 f;
            #pragma unroll
            for (int j = 0; j < 8; ++j) {
                const int k = kh * 32 + 8 * g + j;
                f[j] = (short)f2bf(K[k * 64 + col]);
            }
            bfrag[ct * 2 + kh] = f;
        }
    }

    if (wid >= NTILES) return;
    const int n0 = wid * 16;

    const unsigned* xrow = xh    + (size_t)(n0 + r16) * (D / 2);
    const unsigned* mrow = meanh + (size_t)(n0 + r16) * (D / 2);
    const bf16x8 aS0 = *(const bf16x8*)(xrow + 4 * g);
    const bf16x8 aS1 = *(const bf16x8*)(xrow + 16 + 4 * g);
    const bf16x8 aN0 = *(const bf16x8*)(mrow + 4 * g);
    const bf16x8 aN1 = *(const bf16x8*)(mrow + 16 + 4 * g);

    f32x4 acc[8];
    #pragma unroll
    for (int ct = 0; ct < 8; ++ct) {
        f32x4 c = {0.f, 0.f, 0.f, 0.f};
        c = __builtin_amdgcn_mfma_f32_16x16x32_bf16(ct < 4 ? aS0 : aN0, bfrag[ct * 2 + 0], c, 0, 0, 0);
        c = __builtin_amdgcn_mfma_f32_16x16x32_bf16(ct < 4 ? aS1 : aN1, bfrag[ct * 2 + 1], c, 0, 0, 0);
        acc[ct] = c;
    }

    #pragma unroll
    for (int ct = 0; ct < 8; ++ct) {
        const int col = (ct < 4 ? 0 : 64) + (ct & 3) * 16 + r16;
        const float bj = bias[col];
        #pragma unroll
        for (int r = 0; r < 4; ++r) {
            const int node = n0 + 4 * g + r;
            out[(size_t)node * UNITS + col] = fmaxf(acc[ct][r] + bj, 0.0f);
        }
    }
}

extern "C" void kernel_launch(void* const* d_in, const int* in_sizes, int n_in,
                              void* d_out, int out_size, void* d_ws, size_t ws_size,
                              hipStream_t stream) {
    const float* x     = (const float*)d_in[0];
    const int*   ei    = (const int*)  d_in[1];
    const float* ew    = (const float*)d_in[2];
    const float* skern = (const float*)d_in[3];
    const float* nkern = (const float*)d_in[4];
    const float* bias  = (const float*)d_in[5];
    float* out = (float*)d_out;

    auto align256 = [](size_t v) { return (v + 255) & ~size_t(255); };
    const size_t szM  = align256((size_t)SC_BLOCKS * NB * sizeof(int));   // partials matrix
    const size_t szT  = align256((size_t)NB * sizeof(int));               // bucket totals
    const size_t szNO = align256((size_t)(N_NODES + 1) * sizeof(int));
    const size_t szP  = align256((size_t)N_EDGES * sizeof(ull));
    const size_t szC  = align256((size_t)N_EDGES * sizeof(unsigned));
    const size_t szX  = align256((size_t)N_NODES * (D / 2) * sizeof(unsigned));

    char* w = (char*)d_ws;
    int*      partial = (int*)w;
    int*      btot    = (int*)(w + szM);
    int*      offs    = (int*)(w + szM + szT);
    ull*      packed  = (ull*)(w + szM + szT + szNO);
    unsigned* cedges  = (unsigned*)(w + szM + szT + szNO + szP);
    unsigned* xh      = (unsigned*)(w + szM + szT + szNO + szP + szC);
    unsigned* meanh   = (unsigned*)(w + szM + szT + szNO + szP + szC + szX);
    (void)ws_size; (void)in_sizes; (void)n_in; (void)out_size;

    prep          <<<PREP_BLOCKS, 256, 0, stream>>>(x, xh, ei, partial);
    scan_cols     <<<NB, 256, 0, stream>>>(partial, btot);
    edge_scatter  <<<SC_BLOCKS, SC_THREADS, 0, stream>>>(ei, ew, partial, btot, packed);
    node_sort     <<<NB, NS_THREADS, 0, stream>>>(btot, offs, packed, cedges);
    sage_aggregate<<<(N_NODES * 32 + 255) / 256, 256, 0, stream>>>(xh, offs, cedges, meanh);
    sage_project  <<<PJ_BLOCKS, 256, 0, stream>>>(xh, meanh, skern, nkern, bias, out);
}